// Round 1
// baseline (224.402 us; speedup 1.0000x reference)
//
#include <hip/hip_runtime.h>
#include <hip/hip_bf16.h>

#define NFR  128   // frames
#define NV   8     // voices
#define NB   8     // batch
#define NP   16    // profiles
#define NH   64    // harmonics
#define NHH  65    // harmonics + fundamental
#define NSAMP 32768

// MIN_FREQ = FREQ_INTERVAL = 40/11025
#define MINFREQ_D (40.0/11025.0)
#define PI_D 3.14159265358979323846

// -----------------------------------------------------------------------------
// Kernel 1: per (b,v) row — frame-level freq/amp for all 65 partials + fp64
// half-phase prefixes per segment.
//   fq[row][h][t]  : per-frame frequency (clipped) fp32
//   am[row][h][t]  : per-frame amplitude (clipped*f0_amp) fp32
//   PP[row][h][j]  : j=0..128, HALF of phase prefix at segment starts, fp64
//     j=0   -> 0            (first 128-sample constant segment)
//     j=k+1 -> prefix at start of middle segment k (sample 128+256k)
//     j=128 -> prefix at sample 32640 (last constant segment)
// -----------------------------------------------------------------------------
__global__ __launch_bounds__(128) void precompute_kernel(
    const float* __restrict__ f0, const float* __restrict__ harm,
    const float* __restrict__ prof,
    float* __restrict__ fq, float* __restrict__ am, double* __restrict__ PP)
{
    __shared__ float profS[NP * NH];       // 4 KB
    __shared__ float fqS[NHH][NFR + 1];    // padded: scan reads stride-129

    const int r = blockIdx.x;    // row = b*8+v, 0..63
    const int t = threadIdx.x;   // frame, 0..127

    for (int idx = t; idx < NP * NH; idx += 128) profS[idx] = prof[idx];

    const float re = f0[(r * 2 + 0) * NFR + t];
    const float im = f0[(r * 2 + 1) * NFR + t];
    const double amp0 = (double)re * (double)re + (double)im * (double)im;
    const double ang  = atan2((double)im, (double)re) * (1.0 / PI_D);
    const double freq = MINFREQ_D + ang * ang * MINFREQ_D;

    // softmax over 16 profiles at this (row, frame)
    float hv[NP];
    float mx = -3.0e38f;
    #pragma unroll
    for (int p = 0; p < NP; ++p) {
        hv[p] = harm[(r * NP + p) * NFR + t];
        mx = fmaxf(mx, hv[p]);
    }
    float s = 0.0f;
    #pragma unroll
    for (int p = 0; p < NP; ++p) { hv[p] = expf(hv[p] - mx); s += hv[p]; }
    const float inv = 1.0f / s;
    #pragma unroll
    for (int p = 0; p < NP; ++p) hv[p] *= inv;

    __syncthreads();  // profS ready

    const int base0 = r * NHH * NFR;
    const float freqf = (float)freq;
    fq[base0 + t] = freqf;
    am[base0 + t] = (float)amp0;
    fqS[0][t] = freqf;

    for (int h = 0; h < NH; ++h) {
        float acc = 0.0f;
        #pragma unroll
        for (int p = 0; p < NP; ++p) acc = fmaf(hv[p], profS[p * NH + h], acc);
        acc = fminf(fmaxf(acc, 0.0f), 1.0f);
        double fh = freq * (double)((h + 2) * (h + 2));
        if (fh > 1.0) fh = 1.0;
        const float fhf = (float)fh;
        fq[base0 + (h + 1) * NFR + t] = fhf;
        am[base0 + (h + 1) * NFR + t] = (float)((double)acc * amp0);
        fqS[h + 1][t] = fhf;
    }
    __syncthreads();

    // fp64 prefix scan over 128 segment sums, one thread per partial.
    if (t < NHH) {
        const int pb = (r * NHH + t) * 129;
        double P = 0.0;
        PP[pb + 0] = 0.0;
        float fprev = fqS[t][0];
        P = 64.0 * (double)fprev;              // half of 128*f[0]
        PP[pb + 1] = P;
        for (int k = 1; k <= 127; ++k) {
            const float fcur = fqS[t][k];
            P += 64.0 * ((double)fprev + (double)fcur);  // half of 128*(f[k-1]+f[k])
            PP[pb + k + 1] = P;
            fprev = fcur;
        }
    }
}

// -----------------------------------------------------------------------------
// Kernel 2: one thread per output sample; accumulate 8 voices x 65 partials.
// phase/2 = P2 + dmh*f[k] + (f[k+1]-f[k])*q2   (fp64, exact closed form)
// signal += amp * sin(2*pi*frac(phase/2))
// -----------------------------------------------------------------------------
__global__ __launch_bounds__(256) void synth_kernel(
    const float* __restrict__ fq, const float* __restrict__ am,
    const double* __restrict__ PP, float* __restrict__ out)
{
    const int bb = blockIdx.x >> 7;        // batch 0..7
    const int c  = blockIdx.x & 127;       // chunk 0..127
    const int i  = c * 256 + threadIdx.x;  // sample 0..32767

    int idx0, idx1, jpp;
    double dmh, q2;
    float w;
    if (i < 128) {                         // constant f[0] head
        idx0 = 0; idx1 = 0; jpp = 0;
        dmh = 0.5 * (double)(i + 1); q2 = 0.0; w = 0.0f;
    } else if (i >= 32640) {               // constant f[127] tail
        idx0 = 127; idx1 = 127; jpp = 128;
        dmh = 0.5 * (double)(i - 32640 + 1); q2 = 0.0; w = 0.0f;
    } else {                               // middle segment k, local m
        const int k = (i - 128) >> 8;
        const int m = (i - 128) & 255;
        idx0 = k; idx1 = k + 1; jpp = k + 1;
        const double dm1 = (double)(m + 1);
        dmh = 0.5 * dm1;
        q2  = dm1 * dm1 * (1.0 / 1024.0);  // half of (m+1)^2/512
        w   = ((float)m + 0.5f) * (1.0f / 256.0f);
    }

    float acc = 0.0f;
    const int rb = bb * NV;
    for (int v = 0; v < NV; ++v) {
        const int row = rb + v;
        const float*  fqr = fq + row * NHH * NFR;
        const float*  amr = am + row * NHH * NFR;
        const double* ppr = PP + row * NHH * 129 + jpp;
        #pragma unroll 5
        for (int h = 0; h < NHH; ++h) {
            const float  fk  = fqr[h * NFR + idx0];
            const float  fk1 = fqr[h * NFR + idx1];
            const float  ak  = amr[h * NFR + idx0];
            const float  ak1 = amr[h * NFR + idx1];
            const double P2  = ppr[h * 129];

            double y = fma((double)fk, dmh, P2);
            y = fma((double)fk1 - (double)fk, q2, y);
            const double fr = y - floor(y);           // in [0,1) revolutions
            const float  sv = __sinf(6.283185307179586f * (float)fr);
            const float  amp = fmaf(ak1 - ak, w, ak);
            acc = fmaf(amp, sv, acc);
        }
    }
    out[bb * NSAMP + i] = acc;
}

extern "C" void kernel_launch(void* const* d_in, const int* in_sizes, int n_in,
                              void* d_out, int out_size, void* d_ws, size_t ws_size,
                              hipStream_t stream) {
    const float* f0   = (const float*)d_in[0];   // (8,8,2,128)
    const float* harm = (const float*)d_in[1];   // (8,8,16,128)
    const float* prof = (const float*)d_in[2];   // (16,64)
    float* out = (float*)d_out;                  // (8,1,32768) fp32

    // workspace layout (needs ~8.6 MB)
    float*  fq = (float*)d_ws;                       // 64*65*128 floats
    float*  am = fq + 64 * NHH * NFR;                // 64*65*128 floats
    double* PP = (double*)(am + 64 * NHH * NFR);     // 64*65*129 doubles (8B aligned)

    precompute_kernel<<<64, 128, 0, stream>>>(f0, harm, prof, fq, am, PP);
    synth_kernel<<<NB * (NSAMP / 256), 256, 0, stream>>>(fq, am, PP, out);
}

// Round 2
// 126.292 us; speedup vs baseline: 1.7768x; 1.7768x over previous
//
#include <hip/hip_runtime.h>
#include <hip/hip_bf16.h>

#define NFR  128   // frames
#define NV   8     // voices
#define NB   8     // batch
#define NP   16    // profiles
#define NH   64    // harmonics
#define NHH  65    // harmonics + fundamental
#define NSAMP 32768

// MIN_FREQ = FREQ_INTERVAL = 40/11025
#define MINFREQ_D (40.0/11025.0)
#define PI_D 3.14159265358979323846

// -----------------------------------------------------------------------------
// Kernel 1: per (b,v) row. Computes per-frame freq/amp for 65 partials, then
// writes FRAME-MAJOR tables (h contiguous) + fp64 half-phase prefixes:
//   fqT[row][t][h], amT[row][t][h]          (fp32, h fastest -> coalesced)
//   PP [row][j][h]  j=0..128                (fp64 half-phase prefix at segment
//                                            starts; j=0 head, j=128 tail)
// Values are bitwise-identical to round-1 (absmax margin depends on it).
// -----------------------------------------------------------------------------
__global__ __launch_bounds__(128) void precompute_kernel(
    const float* __restrict__ f0, const float* __restrict__ harm,
    const float* __restrict__ prof,
    float* __restrict__ fqT, float* __restrict__ amT, double* __restrict__ PP)
{
    __shared__ float profS[NP * NH];       // 4 KB
    __shared__ float fqS[NHH][NFR + 1];    // padded: stride 129
    __shared__ float amS[NHH][NFR + 1];

    const int r = blockIdx.x;    // row = b*8+v, 0..63
    const int t = threadIdx.x;   // frame, 0..127

    for (int idx = t; idx < NP * NH; idx += 128) profS[idx] = prof[idx];

    const float re = f0[(r * 2 + 0) * NFR + t];
    const float im = f0[(r * 2 + 1) * NFR + t];
    const double amp0 = (double)re * (double)re + (double)im * (double)im;
    const double ang  = atan2((double)im, (double)re) * (1.0 / PI_D);
    const double freq = MINFREQ_D + ang * ang * MINFREQ_D;

    // softmax over 16 profiles at this (row, frame)
    float hv[NP];
    float mx = -3.0e38f;
    #pragma unroll
    for (int p = 0; p < NP; ++p) {
        hv[p] = harm[(r * NP + p) * NFR + t];
        mx = fmaxf(mx, hv[p]);
    }
    float s = 0.0f;
    #pragma unroll
    for (int p = 0; p < NP; ++p) { hv[p] = expf(hv[p] - mx); s += hv[p]; }
    const float inv = 1.0f / s;
    #pragma unroll
    for (int p = 0; p < NP; ++p) hv[p] *= inv;

    __syncthreads();  // profS ready

    const float freqf = (float)freq;
    fqS[0][t] = freqf;
    amS[0][t] = (float)amp0;

    for (int h = 0; h < NH; ++h) {
        float acc = 0.0f;
        #pragma unroll
        for (int p = 0; p < NP; ++p) acc = fmaf(hv[p], profS[p * NH + h], acc);
        acc = fminf(fmaxf(acc, 0.0f), 1.0f);
        double fh = freq * (double)((h + 2) * (h + 2));
        if (fh > 1.0) fh = 1.0;
        fqS[h + 1][t] = (float)fh;
        amS[h + 1][t] = (float)((double)acc * amp0);
    }
    __syncthreads();

    // write-out: fqT/amT frame-major, h fastest (coalesced)
    for (int e = t; e < NHH * NFR; e += 128) {
        const int h  = e % NHH;
        const int fr = e / NHH;
        fqT[r * NHH * NFR + e] = fqS[h][fr];
        amT[r * NHH * NFR + e] = amS[h][fr];
    }

    // fp64 prefix scan over 128 segment sums, one thread per partial.
    // PP[(r*129 + j)*65 + h]: lanes h write consecutive doubles (coalesced).
    if (t < NHH) {
        const int pb = r * 129 * NHH + t;
        double P = 0.0;
        PP[pb + 0 * NHH] = 0.0;
        float fprev = fqS[t][0];
        P = 64.0 * (double)fprev;              // half of 128*f[0]
        PP[pb + 1 * NHH] = P;
        for (int k = 1; k <= 127; ++k) {
            const float fcur = fqS[t][k];
            P += 64.0 * ((double)fprev + (double)fcur);
            PP[pb + (k + 1) * NHH] = P;
            fprev = fcur;
        }
    }
}

// -----------------------------------------------------------------------------
// Kernel 2: block = (batch, 256-sample chunk). The chunk spans exactly two
// frame-segments (wave-uniform: boundaries are multiples of 64). Stage the
// 2 x 8 voices x 65 partials = 1040 table entries into LDS (33 KB), then each
// thread accumulates its sample over 520 broadcast LDS reads.
//   phase/2 = P2 + fk*(u/2) + df*(u^2/1024)   (fp64, bitwise = round 1)
//   signal += amp * v_sin(frac(phase/2))      (v_sin input is revolutions)
// -----------------------------------------------------------------------------
struct alignas(16) Ent { double p2, fkd, dfd; float ak, dak; };  // 32 B

__global__ __launch_bounds__(256) void synth_kernel(
    const float* __restrict__ fqT, const float* __restrict__ amT,
    const double* __restrict__ PP, float* __restrict__ out)
{
    __shared__ Ent sE[2 * 520];            // 33.3 KB

    const int bb  = blockIdx.x >> 7;       // batch 0..7
    const int c   = blockIdx.x & 127;      // chunk 0..127
    const int tid = threadIdx.x;

    // ---- stage: 1040 entries, coalesced global reads (h contiguous) ----
    for (int e = tid; e < 2 * NV * NHH; e += 256) {
        const int s  = (e >= NV * NHH) ? 1 : 0;
        const int e2 = e - s * NV * NHH;
        const int v  = e2 / NHH;
        const int h  = e2 - v * NHH;
        const int j  = c + s;                        // segment id 0..128
        const int f0i = (j == 0) ? 0 : (j - 1);
        const int f1i = (j >= 128) ? 127 : j;
        const int row = bb * NV + v;
        const float  fk  = fqT[(row * NFR + f0i) * NHH + h];
        const float  fk1 = fqT[(row * NFR + f1i) * NHH + h];
        const float  ak  = amT[(row * NFR + f0i) * NHH + h];
        const float  ak1 = amT[(row * NFR + f1i) * NHH + h];
        const double p2  = PP[(row * 129 + j) * NHH + h];
        Ent en;
        en.p2  = p2;
        en.fkd = (double)fk;
        en.dfd = (double)fk1 - (double)fk;   // exact in f64
        en.ak  = ak;
        en.dak = ak1 - ak;                   // same f32 rounding as round 1
        sE[e] = en;
    }
    __syncthreads();

    // ---- per-thread sample parameters (wave-uniform segment) ----
    const int half = tid >> 7;             // which of the 2 segments
    const int i    = c * 256 + tid;        // sample index
    int u;                                 // samples into segment, 1-based
    if (half) u = tid - 127;
    else      u = (c == 0) ? (tid + 1) : (tid + 129);
    const double uh = 0.5 * (double)u;
    const double uq = (double)(u * u) * (1.0 / 1024.0);
    const float  w  = ((float)u - 0.5f) * (1.0f / 256.0f);  // == (m+0.5)/256

    const Ent* __restrict__ E = sE + half * (NV * NHH);

    float acc = 0.0f;
    #pragma unroll 5
    for (int e = 0; e < NV * NHH; ++e) {
        double y = fma(E[e].fkd, uh, E[e].p2);
        y = fma(E[e].dfd, uq, y);
#if __has_builtin(__builtin_amdgcn_fract)
        const double fr = __builtin_amdgcn_fract(y);   // == y - floor(y)
#else
        const double fr = y - floor(y);
#endif
        const float sv  = __builtin_amdgcn_sinf((float)fr);  // sin(2*pi*x)
        const float amp = fmaf(E[e].dak, w, E[e].ak);
        acc = fmaf(amp, sv, acc);
    }
    out[bb * NSAMP + i] = acc;
}

extern "C" void kernel_launch(void* const* d_in, const int* in_sizes, int n_in,
                              void* d_out, int out_size, void* d_ws, size_t ws_size,
                              hipStream_t stream) {
    const float* f0   = (const float*)d_in[0];   // (8,8,2,128)
    const float* harm = (const float*)d_in[1];   // (8,8,16,128)
    const float* prof = (const float*)d_in[2];   // (16,64)
    float* out = (float*)d_out;                  // (8,1,32768) fp32

    // workspace layout (8.55 MB total, same budget as round 1)
    float*  fqT = (float*)d_ws;                      // 64*128*65 floats
    float*  amT = fqT + 64 * NFR * NHH;              // 64*128*65 floats
    double* PP  = (double*)(amT + 64 * NFR * NHH);   // 64*129*65 doubles

    precompute_kernel<<<64, 128, 0, stream>>>(f0, harm, prof, fqT, amT, PP);
    synth_kernel<<<NB * (NSAMP / 256), 256, 0, stream>>>(fqT, amT, PP, out);
}

// Round 3
// 112.317 us; speedup vs baseline: 1.9979x; 1.1244x over previous
//
#include <hip/hip_runtime.h>
#include <hip/hip_bf16.h>

#define NFR  128   // frames
#define NV   8     // voices
#define NB   8     // batch
#define NP   16    // profiles
#define NH   64    // harmonics
#define NHH  65    // harmonics + fundamental
#define NSAMP 32768

// MIN_FREQ = FREQ_INTERVAL = 40/11025
#define MINFREQ_D (40.0/11025.0)
#define PI_D 3.14159265358979323846

// -----------------------------------------------------------------------------
// Kernel 1: per (b,v) row. Computes per-frame freq/amp for 65 partials, then
// writes FRAME-MAJOR tables (h contiguous) + fp64 half-phase prefixes.
// Values bitwise-identical to rounds 1-2 (absmax margin depends on it).
// -----------------------------------------------------------------------------
__global__ __launch_bounds__(128) void precompute_kernel(
    const float* __restrict__ f0, const float* __restrict__ harm,
    const float* __restrict__ prof,
    float* __restrict__ fqT, float* __restrict__ amT, double* __restrict__ PP)
{
    __shared__ float profS[NP * NH];       // 4 KB
    __shared__ float fqS[NHH][NFR + 1];    // padded: stride 129
    __shared__ float amS[NHH][NFR + 1];

    const int r = blockIdx.x;    // row = b*8+v, 0..63
    const int t = threadIdx.x;   // frame, 0..127

    for (int idx = t; idx < NP * NH; idx += 128) profS[idx] = prof[idx];

    const float re = f0[(r * 2 + 0) * NFR + t];
    const float im = f0[(r * 2 + 1) * NFR + t];
    const double amp0 = (double)re * (double)re + (double)im * (double)im;
    const double ang  = atan2((double)im, (double)re) * (1.0 / PI_D);
    const double freq = MINFREQ_D + ang * ang * MINFREQ_D;

    // softmax over 16 profiles at this (row, frame)
    float hv[NP];
    float mx = -3.0e38f;
    #pragma unroll
    for (int p = 0; p < NP; ++p) {
        hv[p] = harm[(r * NP + p) * NFR + t];
        mx = fmaxf(mx, hv[p]);
    }
    float s = 0.0f;
    #pragma unroll
    for (int p = 0; p < NP; ++p) { hv[p] = expf(hv[p] - mx); s += hv[p]; }
    const float inv = 1.0f / s;
    #pragma unroll
    for (int p = 0; p < NP; ++p) hv[p] *= inv;

    __syncthreads();  // profS ready

    const float freqf = (float)freq;
    fqS[0][t] = freqf;
    amS[0][t] = (float)amp0;

    for (int h = 0; h < NH; ++h) {
        float acc = 0.0f;
        #pragma unroll
        for (int p = 0; p < NP; ++p) acc = fmaf(hv[p], profS[p * NH + h], acc);
        acc = fminf(fmaxf(acc, 0.0f), 1.0f);
        double fh = freq * (double)((h + 2) * (h + 2));
        if (fh > 1.0) fh = 1.0;
        fqS[h + 1][t] = (float)fh;
        amS[h + 1][t] = (float)((double)acc * amp0);
    }
    __syncthreads();

    // write-out: fqT/amT frame-major, h fastest (coalesced)
    for (int e = t; e < NHH * NFR; e += 128) {
        const int h  = e % NHH;
        const int fr = e / NHH;
        fqT[r * NHH * NFR + e] = fqS[h][fr];
        amT[r * NHH * NFR + e] = amS[h][fr];
    }

    // fp64 prefix scan over 128 segment sums, one thread per partial.
    if (t < NHH) {
        const int pb = r * 129 * NHH + t;
        double P = 0.0;
        PP[pb + 0 * NHH] = 0.0;
        float fprev = fqS[t][0];
        P = 64.0 * (double)fprev;              // half of 128*f[0]
        PP[pb + 1 * NHH] = P;
        for (int k = 1; k <= 127; ++k) {
            const float fcur = fqS[t][k];
            P += 64.0 * ((double)fprev + (double)fcur);
            PP[pb + (k + 1) * NHH] = P;
            fprev = fcur;
        }
    }
}

// -----------------------------------------------------------------------------
// Kernel 2: block = (batch, 256-sample chunk), 512 threads =
// 128 sample-pairs x 4 voice-groups (2 voices each). Table (2 segments x
// 8 voices x 65 partials = 1040 entries) staged once into LDS as two 16-B
// arrays; each thread loads an entry once and evaluates TWO samples (2x ILP,
// half the LDS reads per sample). 4 partial sums per sample reduced via LDS.
// Phase math bitwise-identical to round 2:
//   phase/2 = P2 + fk*(u/2) + df*(u^2/1024)   (fp64)
//   signal += amp * v_sin(frac(phase/2))
// -----------------------------------------------------------------------------
struct alignas(16) EntB { double dfd; float ak, dak; };  // 16 B

__global__ __launch_bounds__(512, 8) void synth_kernel(
    const float* __restrict__ fqT, const float* __restrict__ amT,
    const double* __restrict__ PP, float* __restrict__ out)
{
    __shared__ double2 sA[2 * 520];        // {p2, fkd}  16.6 KB
    __shared__ EntB    sB[2 * 520];        // {dfd, ak, dak} 16.6 KB

    const int bb  = blockIdx.x >> 7;       // batch 0..7
    const int c   = blockIdx.x & 127;      // chunk 0..127
    const int tid = threadIdx.x;

    // ---- stage: 1040 entries, coalesced global reads (h contiguous) ----
    for (int e = tid; e < 2 * NV * NHH; e += 512) {
        const int s  = (e >= NV * NHH) ? 1 : 0;
        const int e2 = e - s * NV * NHH;
        const int v  = e2 / NHH;
        const int h  = e2 - v * NHH;
        const int j  = c + s;                        // segment id 0..128
        const int f0i = (j == 0) ? 0 : (j - 1);
        const int f1i = (j >= 128) ? 127 : j;
        const int row = bb * NV + v;
        const float  fk  = fqT[(row * NFR + f0i) * NHH + h];
        const float  fk1 = fqT[(row * NFR + f1i) * NHH + h];
        const float  ak  = amT[(row * NFR + f0i) * NHH + h];
        const float  ak1 = amT[(row * NFR + f1i) * NHH + h];
        const double p2  = PP[(row * 129 + j) * NHH + h];
        double2 ea; ea.x = p2; ea.y = (double)fk;
        EntB    eb; eb.dfd = (double)fk1 - (double)fk; eb.ak = ak; eb.dak = ak1 - ak;
        sA[e] = ea;
        sB[e] = eb;
    }
    __syncthreads();

    // ---- per-thread: sample pair (2p, 2p+1) of this chunk, voices 2g,2g+1 --
    const int p  = tid & 127;              // sample pair 0..127
    const int vg = tid >> 7;               // voice group 0..3 (wave-uniform)
    const int half = p >> 6;               // segment half (wave-uniform)
    const int s0 = 2 * p;                  // local sample 0..254

    int u0;                                // samples into segment, 1-based
    if (half) u0 = s0 - 127;
    else      u0 = (c == 0) ? (s0 + 1) : (s0 + 129);
    const int u1 = u0 + 1;
    const double uh0 = 0.5 * (double)u0;
    const double uq0 = (double)(u0 * u0) * (1.0 / 1024.0);
    const double uh1 = 0.5 * (double)u1;
    const double uq1 = (double)(u1 * u1) * (1.0 / 1024.0);
    const float  w0  = ((float)u0 - 0.5f) * (1.0f / 256.0f);
    const float  w1  = ((float)u1 - 0.5f) * (1.0f / 256.0f);

    const int eb0 = half * (NV * NHH) + vg * (2 * NHH);

    float acc0 = 0.0f, acc1 = 0.0f;
    #pragma unroll 2
    for (int e = 0; e < 2 * NHH; ++e) {
        const double2 ea = sA[eb0 + e];
        const EntB    eb = sB[eb0 + e];
        double y0 = fma(ea.y, uh0, ea.x);
        double y1 = fma(ea.y, uh1, ea.x);
        y0 = fma(eb.dfd, uq0, y0);
        y1 = fma(eb.dfd, uq1, y1);
#if __has_builtin(__builtin_amdgcn_fract)
        const double fr0 = __builtin_amdgcn_fract(y0);
        const double fr1 = __builtin_amdgcn_fract(y1);
#else
        const double fr0 = y0 - floor(y0);
        const double fr1 = y1 - floor(y1);
#endif
        const float sv0 = __builtin_amdgcn_sinf((float)fr0);
        const float sv1 = __builtin_amdgcn_sinf((float)fr1);
        const float amp0 = fmaf(eb.dak, w0, eb.ak);
        const float amp1 = fmaf(eb.dak, w1, eb.ak);
        acc0 = fmaf(amp0, sv0, acc0);
        acc1 = fmaf(amp1, sv1, acc1);
    }

    // ---- reduce 4 voice-group partials per sample via LDS (reuse sA) ----
    __syncthreads();                        // all table reads done
    float* red = (float*)sA;                // 1024 floats
    red[vg * 256 + s0]     = acc0;
    red[vg * 256 + s0 + 1] = acc1;
    __syncthreads();
    if (tid < 256) {
        const float r = ((red[tid] + red[256 + tid]) + red[512 + tid])
                        + red[768 + tid];
        out[bb * NSAMP + c * 256 + tid] = r;
    }
}

extern "C" void kernel_launch(void* const* d_in, const int* in_sizes, int n_in,
                              void* d_out, int out_size, void* d_ws, size_t ws_size,
                              hipStream_t stream) {
    const float* f0   = (const float*)d_in[0];   // (8,8,2,128)
    const float* harm = (const float*)d_in[1];   // (8,8,16,128)
    const float* prof = (const float*)d_in[2];   // (16,64)
    float* out = (float*)d_out;                  // (8,1,32768) fp32

    // workspace layout (8.55 MB total)
    float*  fqT = (float*)d_ws;                      // 64*128*65 floats
    float*  amT = fqT + 64 * NFR * NHH;              // 64*128*65 floats
    double* PP  = (double*)(amT + 64 * NFR * NHH);   // 64*129*65 doubles

    precompute_kernel<<<64, 128, 0, stream>>>(f0, harm, prof, fqT, amT, PP);
    synth_kernel<<<NB * (NSAMP / 256), 512, 0, stream>>>(fqT, amT, PP, out);
}

// Round 4
// 106.632 us; speedup vs baseline: 2.1044x; 1.0533x over previous
//
#include <hip/hip_runtime.h>
#include <hip/hip_bf16.h>

#define NFR  128   // frames
#define NV   8     // voices
#define NB   8     // batch
#define NP   16    // profiles
#define NH   64    // harmonics
#define NHH  65    // harmonics + fundamental
#define NSAMP 32768

// MIN_FREQ = FREQ_INTERVAL = 40/11025
#define MINFREQ_D (40.0/11025.0)
#define PI_D 3.14159265358979323846

// -----------------------------------------------------------------------------
// Kernel 1: per (b,v) row. UNCHANGED from round 3 (tables bitwise identical).
// Writes frame-major fqT/amT (h fastest) + fp64 half-phase prefixes PP.
// -----------------------------------------------------------------------------
__global__ __launch_bounds__(128) void precompute_kernel(
    const float* __restrict__ f0, const float* __restrict__ harm,
    const float* __restrict__ prof,
    float* __restrict__ fqT, float* __restrict__ amT, double* __restrict__ PP)
{
    __shared__ float profS[NP * NH];       // 4 KB
    __shared__ float fqS[NHH][NFR + 1];    // padded: stride 129
    __shared__ float amS[NHH][NFR + 1];

    const int r = blockIdx.x;    // row = b*8+v, 0..63
    const int t = threadIdx.x;   // frame, 0..127

    for (int idx = t; idx < NP * NH; idx += 128) profS[idx] = prof[idx];

    const float re = f0[(r * 2 + 0) * NFR + t];
    const float im = f0[(r * 2 + 1) * NFR + t];
    const double amp0 = (double)re * (double)re + (double)im * (double)im;
    const double ang  = atan2((double)im, (double)re) * (1.0 / PI_D);
    const double freq = MINFREQ_D + ang * ang * MINFREQ_D;

    // softmax over 16 profiles at this (row, frame)
    float hv[NP];
    float mx = -3.0e38f;
    #pragma unroll
    for (int p = 0; p < NP; ++p) {
        hv[p] = harm[(r * NP + p) * NFR + t];
        mx = fmaxf(mx, hv[p]);
    }
    float s = 0.0f;
    #pragma unroll
    for (int p = 0; p < NP; ++p) { hv[p] = expf(hv[p] - mx); s += hv[p]; }
    const float inv = 1.0f / s;
    #pragma unroll
    for (int p = 0; p < NP; ++p) hv[p] *= inv;

    __syncthreads();  // profS ready

    const float freqf = (float)freq;
    fqS[0][t] = freqf;
    amS[0][t] = (float)amp0;

    for (int h = 0; h < NH; ++h) {
        float acc = 0.0f;
        #pragma unroll
        for (int p = 0; p < NP; ++p) acc = fmaf(hv[p], profS[p * NH + h], acc);
        acc = fminf(fmaxf(acc, 0.0f), 1.0f);
        double fh = freq * (double)((h + 2) * (h + 2));
        if (fh > 1.0) fh = 1.0;
        fqS[h + 1][t] = (float)fh;
        amS[h + 1][t] = (float)((double)acc * amp0);
    }
    __syncthreads();

    // write-out: fqT/amT frame-major, h fastest (coalesced)
    for (int e = t; e < NHH * NFR; e += 128) {
        const int h  = e % NHH;
        const int fr = e / NHH;
        fqT[r * NHH * NFR + e] = fqS[h][fr];
        amT[r * NHH * NFR + e] = amS[h][fr];
    }

    // fp64 prefix scan over 128 segment sums, one thread per partial.
    if (t < NHH) {
        const int pb = r * 129 * NHH + t;
        double P = 0.0;
        PP[pb + 0 * NHH] = 0.0;
        float fprev = fqS[t][0];
        P = 64.0 * (double)fprev;              // half of 128*f[0]
        PP[pb + 1 * NHH] = P;
        for (int k = 1; k <= 127; ++k) {
            const float fcur = fqS[t][k];
            P += 64.0 * ((double)fprev + (double)fcur);
            PP[pb + (k + 1) * NHH] = P;
            fprev = fcur;
        }
    }
}

// -----------------------------------------------------------------------------
// Kernel 2: block = (batch, 256-sample chunk), 512 threads =
// 8 voice-lanes x 64 sample-quads. Each thread owns ONE voice and FOUR
// consecutive samples (4 independent sin chains). Hot-loop math is pure f32:
// at stage time p2m = (float)frac(P2_f64) (only frac(phase) matters), then
//   y = p2m + fk*(u/2) + df*(u^2/1024);  signal += amp * v_sin(fract(y))
// f32 rounding at |y|<=193 adds <= ~2e-5 rev/eval -> output shift ~1e-3.
// 8 per-voice partials reduced via LDS.
// -----------------------------------------------------------------------------
__global__ __launch_bounds__(512, 8) void synth_kernel(
    const float* __restrict__ fqT, const float* __restrict__ amT,
    const double* __restrict__ PP, float* __restrict__ out)
{
    __shared__ float4 sE4[2 * 520];        // {fk, df, ak, dak} 16.6 KB
    __shared__ float  sEp[2 * 520];        // p2m               4.2 KB

    const int bb  = blockIdx.x >> 7;       // batch 0..7
    const int c   = blockIdx.x & 127;      // chunk 0..127
    const int tid = threadIdx.x;

    // ---- stage: 1040 entries, coalesced global reads (h contiguous) ----
    for (int e = tid; e < 2 * NV * NHH; e += 512) {
        const int s  = (e >= NV * NHH) ? 1 : 0;
        const int e2 = e - s * NV * NHH;
        const int v  = e2 / NHH;
        const int h  = e2 - v * NHH;
        const int j  = c + s;                        // segment id 0..128
        const int f0i = (j == 0) ? 0 : (j - 1);
        const int f1i = (j >= 128) ? 127 : j;
        const int row = bb * NV + v;
        const float  fk  = fqT[(row * NFR + f0i) * NHH + h];
        const float  fk1 = fqT[(row * NFR + f1i) * NHH + h];
        const float  ak  = amT[(row * NFR + f0i) * NHH + h];
        const float  ak1 = amT[(row * NFR + f1i) * NHH + h];
        const double p2  = PP[(row * 129 + j) * NHH + h];
        sE4[e] = make_float4(fk, fk1 - fk, ak, ak1 - ak);
        sEp[e] = (float)(p2 - floor(p2));
    }
    __syncthreads();

    // ---- per-thread: voice vg, samples 4q..4q+3 of this chunk ----
    const int q  = tid & 63;               // sample quad 0..63
    const int vg = tid >> 6;               // voice 0..7 (wave-uniform)
    const int half = q >> 5;               // segment half (splits wave 32/32)
    const int s0 = 4 * q;                  // local sample 0..252

    int u0;                                // samples into segment, 1-based
    if (half) u0 = s0 - 127;
    else      u0 = (c == 0) ? (s0 + 1) : (s0 + 129);

    float uh[4], uq[4], w[4];
    #pragma unroll
    for (int rr = 0; rr < 4; ++rr) {
        const int u = u0 + rr;
        uh[rr] = 0.5f * (float)u;
        uq[rr] = (float)(u * u) * (1.0f / 1024.0f);
        w[rr]  = ((float)u - 0.5f) * (1.0f / 256.0f);
    }

    const int eb = half * (NV * NHH) + vg * NHH;

    float a0 = 0.0f, a1 = 0.0f, a2 = 0.0f, a3 = 0.0f;
    #pragma unroll 2
    for (int e = 0; e < NHH; ++e) {
        const float4 E  = sE4[eb + e];
        const float p2m = sEp[eb + e];

        float y0 = fmaf(E.x, uh[0], p2m);
        float y1 = fmaf(E.x, uh[1], p2m);
        float y2 = fmaf(E.x, uh[2], p2m);
        float y3 = fmaf(E.x, uh[3], p2m);
        y0 = fmaf(E.y, uq[0], y0);
        y1 = fmaf(E.y, uq[1], y1);
        y2 = fmaf(E.y, uq[2], y2);
        y3 = fmaf(E.y, uq[3], y3);
#if __has_builtin(__builtin_amdgcn_fractf)
        const float fr0 = __builtin_amdgcn_fractf(y0);
        const float fr1 = __builtin_amdgcn_fractf(y1);
        const float fr2 = __builtin_amdgcn_fractf(y2);
        const float fr3 = __builtin_amdgcn_fractf(y3);
#else
        const float fr0 = y0 - floorf(y0);
        const float fr1 = y1 - floorf(y1);
        const float fr2 = y2 - floorf(y2);
        const float fr3 = y3 - floorf(y3);
#endif
        const float sv0 = __builtin_amdgcn_sinf(fr0);  // sin(2*pi*x)
        const float sv1 = __builtin_amdgcn_sinf(fr1);
        const float sv2 = __builtin_amdgcn_sinf(fr2);
        const float sv3 = __builtin_amdgcn_sinf(fr3);
        a0 = fmaf(fmaf(E.w, w[0], E.z), sv0, a0);
        a1 = fmaf(fmaf(E.w, w[1], E.z), sv1, a1);
        a2 = fmaf(fmaf(E.w, w[2], E.z), sv2, a2);
        a3 = fmaf(fmaf(E.w, w[3], E.z), sv3, a3);
    }

    // ---- reduce 8 per-voice partials per sample via LDS (reuse sE4) ----
    __syncthreads();                        // all table reads done
    float4* red4 = (float4*)sE4;            // need 512 float4 = 8 KB
    red4[vg * 64 + q] = make_float4(a0, a1, a2, a3);
    __syncthreads();
    if (tid < 256) {
        const float* red = (const float*)sE4;   // [voice][256]
        float r = red[tid];
        #pragma unroll
        for (int v = 1; v < NV; ++v) r += red[v * 256 + tid];
        out[bb * NSAMP + c * 256 + tid] = r;
    }
}

extern "C" void kernel_launch(void* const* d_in, const int* in_sizes, int n_in,
                              void* d_out, int out_size, void* d_ws, size_t ws_size,
                              hipStream_t stream) {
    const float* f0   = (const float*)d_in[0];   // (8,8,2,128)
    const float* harm = (const float*)d_in[1];   // (8,8,16,128)
    const float* prof = (const float*)d_in[2];   // (16,64)
    float* out = (float*)d_out;                  // (8,1,32768) fp32

    // workspace layout (8.55 MB total)
    float*  fqT = (float*)d_ws;                      // 64*128*65 floats
    float*  amT = fqT + 64 * NFR * NHH;              // 64*128*65 floats
    double* PP  = (double*)(amT + 64 * NFR * NHH);   // 64*129*65 doubles

    precompute_kernel<<<64, 128, 0, stream>>>(f0, harm, prof, fqT, amT, PP);
    synth_kernel<<<NB * (NSAMP / 256), 512, 0, stream>>>(fqT, amT, PP, out);
}

// Round 5
// 94.230 us; speedup vs baseline: 2.3814x; 1.1316x over previous
//
#include <hip/hip_runtime.h>
#include <hip/hip_bf16.h>

#define NFR  128   // frames
#define NV   8     // voices
#define NB   8     // batch
#define NP   16    // profiles
#define NH   64    // harmonics
#define NHH  65    // harmonics + fundamental
#define NSAMP 32768

// MIN_FREQ = FREQ_INTERVAL = 40/11025
#define MINFREQ_D (40.0/11025.0)
#define PI_D 3.14159265358979323846

// -----------------------------------------------------------------------------
// Kernel 1: per (b,v) row. UNCHANGED (tables bitwise identical to rounds 3-4).
// -----------------------------------------------------------------------------
__global__ __launch_bounds__(128) void precompute_kernel(
    const float* __restrict__ f0, const float* __restrict__ harm,
    const float* __restrict__ prof,
    float* __restrict__ fqT, float* __restrict__ amT, double* __restrict__ PP)
{
    __shared__ float profS[NP * NH];       // 4 KB
    __shared__ float fqS[NHH][NFR + 1];    // padded: stride 129
    __shared__ float amS[NHH][NFR + 1];

    const int r = blockIdx.x;    // row = b*8+v, 0..63
    const int t = threadIdx.x;   // frame, 0..127

    for (int idx = t; idx < NP * NH; idx += 128) profS[idx] = prof[idx];

    const float re = f0[(r * 2 + 0) * NFR + t];
    const float im = f0[(r * 2 + 1) * NFR + t];
    const double amp0 = (double)re * (double)re + (double)im * (double)im;
    const double ang  = atan2((double)im, (double)re) * (1.0 / PI_D);
    const double freq = MINFREQ_D + ang * ang * MINFREQ_D;

    // softmax over 16 profiles at this (row, frame)
    float hv[NP];
    float mx = -3.0e38f;
    #pragma unroll
    for (int p = 0; p < NP; ++p) {
        hv[p] = harm[(r * NP + p) * NFR + t];
        mx = fmaxf(mx, hv[p]);
    }
    float s = 0.0f;
    #pragma unroll
    for (int p = 0; p < NP; ++p) { hv[p] = expf(hv[p] - mx); s += hv[p]; }
    const float inv = 1.0f / s;
    #pragma unroll
    for (int p = 0; p < NP; ++p) hv[p] *= inv;

    __syncthreads();  // profS ready

    const float freqf = (float)freq;
    fqS[0][t] = freqf;
    amS[0][t] = (float)amp0;

    for (int h = 0; h < NH; ++h) {
        float acc = 0.0f;
        #pragma unroll
        for (int p = 0; p < NP; ++p) acc = fmaf(hv[p], profS[p * NH + h], acc);
        acc = fminf(fmaxf(acc, 0.0f), 1.0f);
        double fh = freq * (double)((h + 2) * (h + 2));
        if (fh > 1.0) fh = 1.0;
        fqS[h + 1][t] = (float)fh;
        amS[h + 1][t] = (float)((double)acc * amp0);
    }
    __syncthreads();

    // write-out: fqT/amT frame-major, h fastest (coalesced)
    for (int e = t; e < NHH * NFR; e += 128) {
        const int h  = e % NHH;
        const int fr = e / NHH;
        fqT[r * NHH * NFR + e] = fqS[h][fr];
        amT[r * NHH * NFR + e] = amS[h][fr];
    }

    // fp64 prefix scan over 128 segment sums, one thread per partial.
    if (t < NHH) {
        const int pb = r * 129 * NHH + t;
        double P = 0.0;
        PP[pb + 0 * NHH] = 0.0;
        float fprev = fqS[t][0];
        P = 64.0 * (double)fprev;              // half of 128*f[0]
        PP[pb + 1 * NHH] = P;
        for (int k = 1; k <= 127; ++k) {
            const float fcur = fqS[t][k];
            P += 64.0 * ((double)fprev + (double)fcur);
            PP[pb + (k + 1) * NHH] = P;
            fprev = fcur;
        }
    }
}

// -----------------------------------------------------------------------------
// Kernel 2: block = (batch, 256-sample chunk), 512 threads =
// 8 voice-lanes x 64 sample-quads; pure-f32 hot loop as in round 4, PLUS
// zero-entry compaction:
//   Harmonics whose clipped freq == 1.0 across the segment AND whose phase
//   prefix is an exact integer (frac(P2)==0) have fract(y) in {0, 0.5} ->
//   v_sin == +/-0 -> contribution is exactly +/-0.0. These are ~49/65 entries
//   (freq*(idx+1)^2 > 1 for all frames when idx>=16). Detect at stage time
//   (fk==1 && df==0 && p2m==0), compact the per-(segment,voice) list
//   h-order-preserving (16 threads, deterministic), loop only survivors.
//   Skipped terms added exactly +/-0.0 before -> sum is bitwise identical.
// -----------------------------------------------------------------------------
__global__ __launch_bounds__(512, 8) void synth_kernel(
    const float* __restrict__ fqT, const float* __restrict__ amT,
    const double* __restrict__ PP, float* __restrict__ out)
{
    __shared__ float4 sE4[2 * 520];        // {fk, df, ak, dak} 16.6 KB
    __shared__ float  sEp[2 * 520];        // p2m               4.2 KB
    __shared__ int    sCnt[16];            // survivors per (seg,voice)

    const int bb  = blockIdx.x >> 7;       // batch 0..7
    const int c   = blockIdx.x & 127;      // chunk 0..127
    const int tid = threadIdx.x;

    // ---- stage phase 1: 1040 entries, coalesced global reads ----
    for (int e = tid; e < 2 * NV * NHH; e += 512) {
        const int s  = (e >= NV * NHH) ? 1 : 0;
        const int e2 = e - s * NV * NHH;
        const int v  = e2 / NHH;
        const int h  = e2 - v * NHH;
        const int j  = c + s;                        // segment id 0..128
        const int f0i = (j == 0) ? 0 : (j - 1);
        const int f1i = (j >= 128) ? 127 : j;
        const int row = bb * NV + v;
        const float  fk  = fqT[(row * NFR + f0i) * NHH + h];
        const float  fk1 = fqT[(row * NFR + f1i) * NHH + h];
        const float  ak  = amT[(row * NFR + f0i) * NHH + h];
        const float  ak1 = amT[(row * NFR + f1i) * NHH + h];
        const double p2  = PP[(row * 129 + j) * NHH + h];
        sE4[e] = make_float4(fk, fk1 - fk, ak, ak1 - ak);
        sEp[e] = (float)(p2 - floor(p2));
    }
    __syncthreads();

    // ---- stage phase 2: compact zero-contribution entries (16 threads) ----
    if (tid < 16) {
        const int base = (tid >> 3) * (NV * NHH) + (tid & 7) * NHH;
        int cnt = 0;
        for (int h = 0; h < NHH; ++h) {
            const float4 E = sE4[base + h];
            const float  p = sEp[base + h];
            const bool dead = (E.x == 1.0f) && (E.y == 0.0f) && (p == 0.0f);
            if (!dead) {
                if (cnt < h) { sE4[base + cnt] = E; sEp[base + cnt] = p; }
                ++cnt;
            }
        }
        sCnt[tid] = cnt;
    }
    __syncthreads();

    // ---- per-thread: voice vg, samples 4q..4q+3 of this chunk ----
    const int q  = tid & 63;               // sample quad 0..63
    const int vg = tid >> 6;               // voice 0..7 (wave-uniform)
    const int half = q >> 5;               // segment half (splits wave 32/32)
    const int s0 = 4 * q;                  // local sample 0..252

    int u0;                                // samples into segment, 1-based
    if (half) u0 = s0 - 127;
    else      u0 = (c == 0) ? (s0 + 1) : (s0 + 129);

    float uh[4], uq[4], w[4];
    #pragma unroll
    for (int rr = 0; rr < 4; ++rr) {
        const int u = u0 + rr;
        uh[rr] = 0.5f * (float)u;
        uq[rr] = (float)(u * u) * (1.0f / 1024.0f);
        w[rr]  = ((float)u - 0.5f) * (1.0f / 256.0f);
    }

    const int eb   = half * (NV * NHH) + vg * NHH;
    const int myCnt = sCnt[half * 8 + vg];

    float a0 = 0.0f, a1 = 0.0f, a2 = 0.0f, a3 = 0.0f;
    for (int e = 0; e < myCnt; ++e) {
        const float4 E  = sE4[eb + e];
        const float p2m = sEp[eb + e];

        float y0 = fmaf(E.x, uh[0], p2m);
        float y1 = fmaf(E.x, uh[1], p2m);
        float y2 = fmaf(E.x, uh[2], p2m);
        float y3 = fmaf(E.x, uh[3], p2m);
        y0 = fmaf(E.y, uq[0], y0);
        y1 = fmaf(E.y, uq[1], y1);
        y2 = fmaf(E.y, uq[2], y2);
        y3 = fmaf(E.y, uq[3], y3);
#if __has_builtin(__builtin_amdgcn_fractf)
        const float fr0 = __builtin_amdgcn_fractf(y0);
        const float fr1 = __builtin_amdgcn_fractf(y1);
        const float fr2 = __builtin_amdgcn_fractf(y2);
        const float fr3 = __builtin_amdgcn_fractf(y3);
#else
        const float fr0 = y0 - floorf(y0);
        const float fr1 = y1 - floorf(y1);
        const float fr2 = y2 - floorf(y2);
        const float fr3 = y3 - floorf(y3);
#endif
        const float sv0 = __builtin_amdgcn_sinf(fr0);  // sin(2*pi*x)
        const float sv1 = __builtin_amdgcn_sinf(fr1);
        const float sv2 = __builtin_amdgcn_sinf(fr2);
        const float sv3 = __builtin_amdgcn_sinf(fr3);
        a0 = fmaf(fmaf(E.w, w[0], E.z), sv0, a0);
        a1 = fmaf(fmaf(E.w, w[1], E.z), sv1, a1);
        a2 = fmaf(fmaf(E.w, w[2], E.z), sv2, a2);
        a3 = fmaf(fmaf(E.w, w[3], E.z), sv3, a3);
    }

    // ---- reduce 8 per-voice partials per sample via LDS (reuse sE4) ----
    __syncthreads();                        // all table reads done
    float4* red4 = (float4*)sE4;            // 512 float4 = 8 KB
    red4[vg * 64 + q] = make_float4(a0, a1, a2, a3);
    __syncthreads();
    if (tid < 256) {
        const float* red = (const float*)sE4;   // [voice][256]
        float r = red[tid];
        #pragma unroll
        for (int v = 1; v < NV; ++v) r += red[v * 256 + tid];
        out[bb * NSAMP + c * 256 + tid] = r;
    }
}

extern "C" void kernel_launch(void* const* d_in, const int* in_sizes, int n_in,
                              void* d_out, int out_size, void* d_ws, size_t ws_size,
                              hipStream_t stream) {
    const float* f0   = (const float*)d_in[0];   // (8,8,2,128)
    const float* harm = (const float*)d_in[1];   // (8,8,16,128)
    const float* prof = (const float*)d_in[2];   // (16,64)
    float* out = (float*)d_out;                  // (8,1,32768) fp32

    // workspace layout (8.55 MB total)
    float*  fqT = (float*)d_ws;                      // 64*128*65 floats
    float*  amT = fqT + 64 * NFR * NHH;              // 64*128*65 floats
    double* PP  = (double*)(amT + 64 * NFR * NHH);   // 64*129*65 doubles

    precompute_kernel<<<64, 128, 0, stream>>>(f0, harm, prof, fqT, amT, PP);
    synth_kernel<<<NB * (NSAMP / 256), 512, 0, stream>>>(fqT, amT, PP, out);
}

// Round 6
// 76.215 us; speedup vs baseline: 2.9443x; 1.2364x over previous
//
#include <hip/hip_runtime.h>
#include <hip/hip_bf16.h>

#define NFR  128   // frames
#define NV   8     // voices
#define NB   8     // batch
#define NP   16    // profiles
#define NI   16    // surviving table entries: for i>=16, ratio^2>=289 and
                   // freq*289 >= 0.00363*289 = 1.0485 > 1 at EVERY frame ->
                   // clipped to 1.0 everywhere -> integer phase prefixes ->
                   // contribution exactly +/-0 (hardware-verified round 5).
#define NSAMP 32768

// MIN_FREQ = FREQ_INTERVAL = 40/11025
#define MINFREQ_D (40.0/11025.0)
#define PI_D 3.14159265358979323846

// -----------------------------------------------------------------------------
// Kernel 1: per (b,v) row. Computes freq/amp for the 16 live partials only
// (same fp64 arithmetic as rounds 1-5 -> bitwise-identical values), runs the
// fp64 half-phase prefix scan, and emits a PACKED per-(row, segment) table:
//   E4[row][j][i] = {fk, df, ak, dak}   (float4)   j = 0..128 segments
//   Ep[row][j][i] = frac(P2)            (float)
// -----------------------------------------------------------------------------
__global__ __launch_bounds__(128) void precompute_kernel(
    const float* __restrict__ f0, const float* __restrict__ harm,
    const float* __restrict__ prof,
    float4* __restrict__ E4, float* __restrict__ Ep)
{
    __shared__ float profS[NP * 64];        // full profile matrix, 4 KB
    __shared__ float fqS[NI][NFR + 1];      // 16 x 129 (padded)
    __shared__ float amS[NI][NFR + 1];
    __shared__ float ppS[NFR + 1][NI];      // frac(P2) per (segment j, i)

    const int r = blockIdx.x;    // row = b*8+v, 0..63
    const int t = threadIdx.x;   // frame, 0..127

    for (int idx = t; idx < NP * 64; idx += 128) profS[idx] = prof[idx];

    const float re = f0[(r * 2 + 0) * NFR + t];
    const float im = f0[(r * 2 + 1) * NFR + t];
    const double amp0 = (double)re * (double)re + (double)im * (double)im;
    const double ang  = atan2((double)im, (double)re) * (1.0 / PI_D);
    const double freq = MINFREQ_D + ang * ang * MINFREQ_D;

    // softmax over 16 profiles at this (row, frame) — identical to round 5
    float hv[NP];
    float mx = -3.0e38f;
    #pragma unroll
    for (int p = 0; p < NP; ++p) {
        hv[p] = harm[(r * NP + p) * NFR + t];
        mx = fmaxf(mx, hv[p]);
    }
    float s = 0.0f;
    #pragma unroll
    for (int p = 0; p < NP; ++p) { hv[p] = expf(hv[p] - mx); s += hv[p]; }
    const float inv = 1.0f / s;
    #pragma unroll
    for (int p = 0; p < NP; ++p) hv[p] *= inv;

    __syncthreads();  // profS ready

    fqS[0][t] = (float)freq;
    amS[0][t] = (float)amp0;

    // only harmonics h=0..14 (table i=1..15) can ever be unclipped
    for (int h = 0; h < NI - 1; ++h) {
        float acc = 0.0f;
        #pragma unroll
        for (int p = 0; p < NP; ++p) acc = fmaf(hv[p], profS[p * 64 + h], acc);
        acc = fminf(fmaxf(acc, 0.0f), 1.0f);
        double fh = freq * (double)((h + 2) * (h + 2));
        if (fh > 1.0) fh = 1.0;
        fqS[h + 1][t] = (float)fh;
        amS[h + 1][t] = (float)((double)acc * amp0);
    }
    __syncthreads();

    // fp64 prefix scan over 128 segment half-sums, one thread per partial.
    // Same accumulation order as rounds 1-5 (bitwise identical).
    if (t < NI) {
        double P = 0.0;
        ppS[0][t] = 0.0f;
        float fprev = fqS[t][0];
        P = 64.0 * (double)fprev;              // half of 128*f[0]
        ppS[1][t] = (float)(P - floor(P));
        for (int k = 1; k <= 127; ++k) {
            const float fcur = fqS[t][k];
            P += 64.0 * ((double)fprev + (double)fcur);
            ppS[k + 1][t] = (float)(P - floor(P));
            fprev = fcur;
        }
    }
    __syncthreads();

    // packed write-out: 129 segments x 16 entries, coalesced float4 stores
    const int base = r * 129 * NI;
    for (int e = t; e < 129 * NI; e += 128) {
        const int j = e >> 4;
        const int i = e & (NI - 1);
        const int f0i = (j == 0) ? 0 : (j - 1);
        const int f1i = (j >= 128) ? 127 : j;
        const float fk  = fqS[i][f0i];
        const float fk1 = fqS[i][f1i];
        const float ak  = amS[i][f0i];
        const float ak1 = amS[i][f1i];
        E4[base + e] = make_float4(fk, fk1 - fk, ak, ak1 - ak);
        Ep[base + e] = ppS[j][i];
    }
}

// -----------------------------------------------------------------------------
// Kernel 2: block = (batch, 256-sample chunk), 512 threads =
// 8 voice-lanes x 64 sample-quads. Stages 2 segs x 8 voices x 16 entries
// (one float4+float per thread, coalesced), then a STATIC 16-iteration
// pure-f32 loop (identical math to rounds 4-5):
//   y = p2m + fk*(u/2) + df*(u^2/1024);  signal += amp * v_sin(fract(y))
// 8 per-voice partials reduced via LDS.
// -----------------------------------------------------------------------------
__global__ __launch_bounds__(512, 8) void synth_kernel(
    const float4* __restrict__ E4, const float* __restrict__ Ep,
    float* __restrict__ out)
{
    __shared__ float4 sE4[512];            // entries in [0,256); reduce scratch
    __shared__ float  sEp[256];

    const int bb  = blockIdx.x >> 7;       // batch 0..7
    const int c   = blockIdx.x & 127;      // chunk 0..127
    const int tid = threadIdx.x;

    // ---- stage: 256 packed entries ----
    if (tid < 256) {
        const int s = tid >> 7;                    // segment half
        const int v = (tid >> 4) & 7;              // voice
        const int i = tid & (NI - 1);              // partial
        const int idx = ((bb * NV + v) * 129 + (c + s)) * NI + i;
        sE4[tid] = E4[idx];
        sEp[tid] = Ep[idx];
    }
    __syncthreads();

    // ---- per-thread: voice vg, samples 4q..4q+3 of this chunk ----
    const int q  = tid & 63;               // sample quad 0..63
    const int vg = tid >> 6;               // voice 0..7 (wave-uniform)
    const int half = q >> 5;               // segment half (splits wave 32/32)
    const int s0 = 4 * q;                  // local sample 0..252

    int u0;                                // samples into segment, 1-based
    if (half) u0 = s0 - 127;
    else      u0 = (c == 0) ? (s0 + 1) : (s0 + 129);

    float uh[4], uq[4], w[4];
    #pragma unroll
    for (int rr = 0; rr < 4; ++rr) {
        const int u = u0 + rr;
        uh[rr] = 0.5f * (float)u;
        uq[rr] = (float)(u * u) * (1.0f / 1024.0f);
        w[rr]  = ((float)u - 0.5f) * (1.0f / 256.0f);
    }

    const int eb = half * (NV * NI) + vg * NI;

    float a0 = 0.0f, a1 = 0.0f, a2 = 0.0f, a3 = 0.0f;
    #pragma unroll 4
    for (int e = 0; e < NI; ++e) {
        const float4 E  = sE4[eb + e];
        const float p2m = sEp[eb + e];

        float y0 = fmaf(E.x, uh[0], p2m);
        float y1 = fmaf(E.x, uh[1], p2m);
        float y2 = fmaf(E.x, uh[2], p2m);
        float y3 = fmaf(E.x, uh[3], p2m);
        y0 = fmaf(E.y, uq[0], y0);
        y1 = fmaf(E.y, uq[1], y1);
        y2 = fmaf(E.y, uq[2], y2);
        y3 = fmaf(E.y, uq[3], y3);
#if __has_builtin(__builtin_amdgcn_fractf)
        const float fr0 = __builtin_amdgcn_fractf(y0);
        const float fr1 = __builtin_amdgcn_fractf(y1);
        const float fr2 = __builtin_amdgcn_fractf(y2);
        const float fr3 = __builtin_amdgcn_fractf(y3);
#else
        const float fr0 = y0 - floorf(y0);
        const float fr1 = y1 - floorf(y1);
        const float fr2 = y2 - floorf(y2);
        const float fr3 = y3 - floorf(y3);
#endif
        const float sv0 = __builtin_amdgcn_sinf(fr0);  // sin(2*pi*x)
        const float sv1 = __builtin_amdgcn_sinf(fr1);
        const float sv2 = __builtin_amdgcn_sinf(fr2);
        const float sv3 = __builtin_amdgcn_sinf(fr3);
        a0 = fmaf(fmaf(E.w, w[0], E.z), sv0, a0);
        a1 = fmaf(fmaf(E.w, w[1], E.z), sv1, a1);
        a2 = fmaf(fmaf(E.w, w[2], E.z), sv2, a2);
        a3 = fmaf(fmaf(E.w, w[3], E.z), sv3, a3);
    }

    // ---- reduce 8 per-voice partials per sample via LDS (reuse sE4) ----
    __syncthreads();                        // all table reads done
    float4* red4 = (float4*)sE4;            // 512 float4 = 8 KB
    red4[vg * 64 + q] = make_float4(a0, a1, a2, a3);
    __syncthreads();
    if (tid < 256) {
        const float* red = (const float*)sE4;   // [voice][256]
        float r = red[tid];
        #pragma unroll
        for (int v = 1; v < NV; ++v) r += red[v * 256 + tid];
        out[bb * NSAMP + c * 256 + tid] = r;
    }
}

extern "C" void kernel_launch(void* const* d_in, const int* in_sizes, int n_in,
                              void* d_out, int out_size, void* d_ws, size_t ws_size,
                              hipStream_t stream) {
    const float* f0   = (const float*)d_in[0];   // (8,8,2,128)
    const float* harm = (const float*)d_in[1];   // (8,8,16,128)
    const float* prof = (const float*)d_in[2];   // (16,64)
    float* out = (float*)d_out;                  // (8,1,32768) fp32

    // workspace layout: packed entry table only (~2.6 MB)
    float4* E4 = (float4*)d_ws;                  // 64*129*16 float4
    float*  Ep = (float*)(E4 + 64 * 129 * NI);   // 64*129*16 floats

    precompute_kernel<<<64, 128, 0, stream>>>(f0, harm, prof, E4, Ep);
    synth_kernel<<<NB * (NSAMP / 256), 512, 0, stream>>>(E4, Ep, out);
}